// Round 7
// baseline (2152.514 us; speedup 1.0000x reference)
//
#include <hip/hip_runtime.h>
#include <float.h>

#pragma clang fp contract(off)

#define B_ 16
#define N_ 4096
#define M_ 1024
#define K_ 32
#define FEAT_ 64
#define H_ 128
#define GEO_IN_ 160
#define GEO_MID_ 130
#define FEAT_IN_ 2048

typedef unsigned short u16t;
typedef float f32x2 __attribute__((ext_vector_type(2)));

// ---- wave64 reductions in the VALU pipe (DPP), identity-preserving ----
#define DPP_STEP_MAX(ctrl) \
  t=(unsigned)__builtin_amdgcn_update_dpp((int)v,(int)v,(ctrl),0xf,0xf,false); \
  v=(t>v)?t:v;
#define DPP_STEP_MIN(ctrl) \
  t=(unsigned)__builtin_amdgcn_update_dpp((int)v,(int)v,(ctrl),0xf,0xf,false); \
  v=(t<v)?t:v;

__device__ __forceinline__ unsigned wave_max_u32(unsigned v){
  unsigned t;
  DPP_STEP_MAX(0x111) DPP_STEP_MAX(0x112) DPP_STEP_MAX(0x114) DPP_STEP_MAX(0x118)
  DPP_STEP_MAX(0x142) DPP_STEP_MAX(0x143)
  return (unsigned)__builtin_amdgcn_readlane((int)v,63);
}
__device__ __forceinline__ unsigned wave_min_u32(unsigned v){
  unsigned t;
  DPP_STEP_MIN(0x111) DPP_STEP_MIN(0x112) DPP_STEP_MIN(0x114) DPP_STEP_MIN(0x118)
  DPP_STEP_MIN(0x142) DPP_STEP_MIN(0x143)
  return (unsigned)__builtin_amdgcn_readlane((int)v,63);
}

// ---------------------------------------------------------------- FPS v3
// 256 thr (4 waves, 1/SIMD — r6 showed 2 waves/SIMD adds lockstep barrier
// cost, no hiding). 16 pts/thread as 8 packed f32x2 pairs: v_pk_* halves
// dist-update issue. Packed-vs-scalar numerics verified bit-identical on HW
// (r2/r4 bisection). Pair p holds pts j=p (x) and j=p+8 (y): all x-half
// indices < y-half for a lane; strict-> in-loop argmax keeps smallest p per
// half; final combine prefers x on tie => exact sequential tie semantics.
// Selection: 1x DPP max + ballot; unique winner (common) publishes directly
// -- second DPP min chain only on rare cross-lane dist ties. Publish =
// key(dist|~idx) + float4 coords; 4-way merge reads keys and coords in
// PARALLEL (no dependent LDS read -- r6's mistake). One barrier/step,
// double-buffered records.
__global__ __launch_bounds__(256) void fps_kernel(
    const float* __restrict__ xyz, float* __restrict__ outc)
{
  const int b = blockIdx.x, tid = threadIdx.x;
  const int wv = tid >> 6;
  const float* xb = xyz + (size_t)b * (N_*3);
  __shared__ unsigned long long kkey[2][4];
  __shared__ __align__(16) float4 kxyz[2][4];
  __shared__ float clist[M_][3];          // 12 KB

  f32x2 PX[8], PY[8], PZ[8], DD[8];
#pragma unroll
  for (int p=0;p<8;p++){
    int i0 = (tid + 256*p)*3, i1 = (tid + 256*(p+8))*3;
    PX[p] = (f32x2){xb[i0],   xb[i1]};
    PY[p] = (f32x2){xb[i0+1], xb[i1+1]};
    PZ[p] = (f32x2){xb[i0+2], xb[i1+2]};
    DD[p] = (f32x2){FLT_MAX, FLT_MAX};
  }
  float lx=xb[0], ly=xb[1], lz=xb[2];
  if (tid==0){ clist[0][0]=lx; clist[0][1]=ly; clist[0][2]=lz; }

  for (int t=1;t<M_;t++){
    f32x2 lxv=(f32x2){lx,lx}, lyv=(f32x2){ly,ly}, lzv=(f32x2){lz,lz};
    f32x2 bd2=(f32x2){-FLT_MAX,-FLT_MAX};
    int bpx=0, bpy=0;
#pragma unroll
    for (int p=0;p<8;p++){
      f32x2 dx=PX[p]-lxv, dy=PY[p]-lyv, dz=PZ[p]-lzv;
      f32x2 s=(dx*dx+dy*dy)+dz*dz;            // same op order as scalar _rn chain
      f32x2 nd=__builtin_elementwise_min(DD[p], s);
      DD[p]=nd;
      if (nd.x>bd2.x){ bd2.x=nd.x; bpx=p; }   // strict > keeps smallest p
      if (nd.y>bd2.y){ bd2.y=nd.y; bpy=p; }
    }
    bool ywin = (bd2.y > bd2.x);              // tie -> x-half (smaller idx)
    float bd = ywin ? bd2.y : bd2.x;
    int   bp = ywin ? bpy   : bpx;
    int   bi = tid + 256*(ywin ? bp+8 : bp);
    unsigned db = __float_as_uint(bd);        // bd>=0 => bit order monotone
    unsigned smax = wave_max_u32(db);
    unsigned long long mask = __ballot(db==smax);
    bool iswin;
    if (mask & (mask-1)){                     // rare: cross-lane dist tie
      unsigned cand = (db==smax) ? (unsigned)bi : 0x7FFFFFFFu;
      unsigned sbi = wave_min_u32(cand);
      iswin = (db==smax) && ((unsigned)bi==sbi);
    } else {
      iswin = (db==smax);                     // unique winner lane
    }
    if (iswin){
      f32x2 wx2=PX[bp], wy2=PY[bp], wz2=PZ[bp];   // movrel dynamic index
      float wx = ywin ? wx2.y : wx2.x;
      float wy = ywin ? wy2.y : wy2.x;
      float wz = ywin ? wz2.y : wz2.x;
      kkey[t&1][wv] = ((unsigned long long)smax<<32) | (unsigned)(0xFFFFFFFFu-(unsigned)bi);
      kxyz[t&1][wv] = make_float4(wx,wy,wz,0.f);
    }
    __syncthreads();
    const unsigned long long* kp = kkey[t&1];
    const float4* cp = kxyz[t&1];
    unsigned long long k0=kp[0],k1=kp[1],k2=kp[2],k3=kp[3];
    float4 c0=cp[0],c1=cp[1],c2=cp[2],c3=cp[3];
    if (k1>k0){ k0=k1; c0=c1; }
    if (k3>k2){ k2=k3; c2=c3; }
    if (k2>k0){ k0=k2; c0=c2; }
    lx=c0.x; ly=c0.y; lz=c0.z;
    if (tid==0){ clist[t][0]=lx; clist[t][1]=ly; clist[t][2]=lz; }
  }
  __syncthreads();
  for (int e=tid; e<M_; e+=256){
    size_t cb=((size_t)b*M_+(size_t)e)*3;
    outc[cb]=clist[e][0]; outc[cb+1]=clist[e][1]; outc[cb+2]=clist[e][2];
  }
}

// ---------------------------------------------------------------- KNN
// PROVEN version. One wave per centroid. 64 dists/lane in registers.
// Selection: 2x u32 DPP (min dist, then min idx among ties). Owner-lane
// rescan as exclusion + fminf min-tree + descending first-match index pass.
__global__ __launch_bounds__(256) void knn_kernel(
    const float* __restrict__ xyz, const float* __restrict__ outc,
    u16t* __restrict__ gidx16)
{
  const int w = blockIdx.x*4 + (threadIdx.x>>6);
  const int lane = threadIdx.x & 63;
  const int b = w >> 10;
  const float* xb = xyz + (size_t)b*(N_*3);
  float cx=outc[(size_t)w*3], cy=outc[(size_t)w*3+1], cz=outc[(size_t)w*3+2];
  float c2=__fadd_rn(__fadd_rn(__fmul_rn(cx,cx),__fmul_rn(cy,cy)),__fmul_rn(cz,cz));
  float dl[64];
  float lv=FLT_MAX; int lj=0;
#pragma unroll
  for (int j=0;j<64;j++){
    int i = lane + 64*j;
    float xx=xb[i*3], xy=xb[i*3+1], xz=xb[i*3+2];
    float x2=__fadd_rn(__fadd_rn(__fmul_rn(xx,xx),__fmul_rn(xy,xy)),__fmul_rn(xz,xz));
    float dt=__fadd_rn(__fadd_rn(__fmul_rn(cx,xx),__fmul_rn(cy,xy)),__fmul_rn(cz,xz));
    float d=__fsub_rn(__fadd_rn(c2,x2),__fmul_rn(2.f,dt));
    dl[j]=d;
    if (d<lv){ lv=d; lj=j; }
  }
  const int wb = w*K_;
  for (int k=0;k<K_;k++){
    unsigned u=__float_as_uint(lv);
    u = (u&0x80000000u) ? ~u : (u|0x80000000u);   // order-preserving
    unsigned smin=wave_min_u32(u);
    unsigned cand=(u==smin)?(unsigned)(lane+64*lj):0xFFFFFFFFu;
    unsigned widx=wave_min_u32(cand);
    if (lane==0) gidx16[wb+k]=(u16t)widx;
    if ((widx & 63)==(unsigned)lane){
      int slot=(int)(widx>>6);
#pragma unroll
      for (int j=0;j<64;j++) dl[j]=(j==slot)?FLT_MAX:dl[j];
      float m01[32];
#pragma unroll
      for (int j=0;j<32;j++) m01[j]=fminf(dl[2*j],dl[2*j+1]);
#pragma unroll
      for (int j=0;j<16;j++) m01[j]=fminf(m01[2*j],m01[2*j+1]);
#pragma unroll
      for (int j=0;j<8;j++)  m01[j]=fminf(m01[2*j],m01[2*j+1]);
#pragma unroll
      for (int j=0;j<4;j++)  m01[j]=fminf(m01[2*j],m01[2*j+1]);
      float nv=fminf(fminf(m01[0],m01[1]),fminf(m01[2],m01[3]));
      int nj=63;
#pragma unroll
      for (int j=62;j>=0;j--) nj=(dl[j]==nv)?j:nj;
      lv=nv; lj=nj;
    }
  }
}

// ---------------------------------------------------------------- GEO fused (GEMM-style)
// (unchanged, proven)
__global__ __launch_bounds__(256) void geo_kernel(
    const float* __restrict__ xyz, const float* __restrict__ outc,
    const u16t* __restrict__ gidx16, const float* __restrict__ W1,
    const float* __restrict__ Wout, float* __restrict__ xout)
{
  __shared__ float smem[160*33 + 64*128 + 32];
  float (*Es)[33]  = (float(*)[33])smem;
  float (*Hs)[33]  = (float(*)[33])smem;
  float (*Ws)[128] = (float(*)[128])(smem + 160*33);
  float* ssv = smem + 160*33 + 64*128;

  const int t=threadIdx.x;
  const int g0=blockIdx.x*32;
  for (int p=t; p<1024; p+=256){
    int g=p>>5, kk=p&31;
    int gg=g0+g, b=gg>>10;
    int idx=gidx16[gg*K_+kk];
    const float* pt = xyz + ((size_t)b*N_+(size_t)idx)*3;
    const float* cc = outc + (size_t)gg*3;
    float dx=__fsub_rn(pt[0],cc[0]);
    float dy=__fsub_rn(pt[1],cc[1]);
    float dz=__fsub_rn(pt[2],cc[2]);
    float sq=__fadd_rn(__fadd_rn(__fmul_rn(dx,dx),__fmul_rn(dy,dy)),__fmul_rn(dz,dz));
    int r=5*kk;
    Es[r][g]=dx; Es[r+1][g]=dy; Es[r+2][g]=dz;
    Es[r+3][g]=-1.f; Es[r+4][g]=__fmul_rn(-0.5f,sq);
  }
  const int gsub=t>>4, hsub=t&15, h0=hsub*8;
  const int hw=t>>1;
  float acc[2][8];
#pragma unroll
  for (int a=0;a<2;a++)
#pragma unroll
    for (int j=0;j<8;j++) acc[a][j]=0.f;
  __syncthreads();

  for (int c=0;c<3;c++){
    int i0=c*64;
    if (c<2){
      int fw0=(t&1)*32;
      const float* wr = W1 + (size_t)hw*GEO_IN_ + i0 + fw0;
      float4 wv[8];
#pragma unroll
      for (int e=0;e<8;e++) wv[e]=((const float4*)wr)[e];
#pragma unroll
      for (int e=0;e<8;e++){
        Ws[fw0+4*e+0][hw]=wv[e].x;
        Ws[fw0+4*e+1][hw]=wv[e].y;
        Ws[fw0+4*e+2][hw]=wv[e].z;
        Ws[fw0+4*e+3][hw]=wv[e].w;
      }
    } else {
      int fw0=(t&1)*16;
      const float* wr = W1 + (size_t)hw*GEO_IN_ + 128 + fw0;
      float4 wv[4];
#pragma unroll
      for (int e=0;e<4;e++) wv[e]=((const float4*)wr)[e];
#pragma unroll
      for (int e=0;e<4;e++){
        Ws[fw0+4*e+0][hw]=wv[e].x;
        Ws[fw0+4*e+1][hw]=wv[e].y;
        Ws[fw0+4*e+2][hw]=wv[e].z;
        Ws[fw0+4*e+3][hw]=wv[e].w;
      }
    }
    __syncthreads();
    int len=(c==2)?32:64;
    for (int k2=0;k2<len;k2++){
      float x0=Es[i0+k2][2*gsub], x1=Es[i0+k2][2*gsub+1];
      const float* wp=&Ws[k2][h0];
      float4 wa=*(const float4*)wp;
      float4 wb=*(const float4*)(wp+4);
      acc[0][0]=__builtin_fmaf(x0,wa.x,acc[0][0]);
      acc[0][1]=__builtin_fmaf(x0,wa.y,acc[0][1]);
      acc[0][2]=__builtin_fmaf(x0,wa.z,acc[0][2]);
      acc[0][3]=__builtin_fmaf(x0,wa.w,acc[0][3]);
      acc[0][4]=__builtin_fmaf(x0,wb.x,acc[0][4]);
      acc[0][5]=__builtin_fmaf(x0,wb.y,acc[0][5]);
      acc[0][6]=__builtin_fmaf(x0,wb.z,acc[0][6]);
      acc[0][7]=__builtin_fmaf(x0,wb.w,acc[0][7]);
      acc[1][0]=__builtin_fmaf(x1,wa.x,acc[1][0]);
      acc[1][1]=__builtin_fmaf(x1,wa.y,acc[1][1]);
      acc[1][2]=__builtin_fmaf(x1,wa.z,acc[1][2]);
      acc[1][3]=__builtin_fmaf(x1,wa.w,acc[1][3]);
      acc[1][4]=__builtin_fmaf(x1,wb.x,acc[1][4]);
      acc[1][5]=__builtin_fmaf(x1,wb.y,acc[1][5]);
      acc[1][6]=__builtin_fmaf(x1,wb.z,acc[1][6]);
      acc[1][7]=__builtin_fmaf(x1,wb.w,acc[1][7]);
    }
    __syncthreads();
  }
#pragma unroll
  for (int a=0;a<2;a++)
#pragma unroll
    for (int j=0;j<8;j++)
      Hs[h0+j][2*gsub+a]=acc[a][j];
  __syncthreads();
  if (t<32){
    float ss=0.f;
    for (int h=0;h<H_;h++){ float v=Hs[h][t]; ss=__builtin_fmaf(v,v,ss); }
    ssv[t]=__fmul_rn(-0.5f,ss);
  }
#pragma unroll
  for (int a=0;a<2;a++)
#pragma unroll
    for (int j=0;j<8;j++) acc[a][j]=0.f;
  for (int c=0;c<2;c++){
    int i0=c*64;
    int fw0=(t&1)*32;
    const float* wr = Wout + (size_t)hw*GEO_MID_ + i0 + fw0;
    float2 wv2[16];
#pragma unroll
    for (int e=0;e<16;e++) wv2[e]=((const float2*)wr)[e];
    __syncthreads();
#pragma unroll
    for (int e=0;e<16;e++){
      Ws[fw0+2*e+0][hw]=wv2[e].x;
      Ws[fw0+2*e+1][hw]=wv2[e].y;
    }
    __syncthreads();
    for (int k2=0;k2<64;k2++){
      float x0=Hs[i0+k2][2*gsub], x1=Hs[i0+k2][2*gsub+1];
      const float* wp=&Ws[k2][h0];
      float4 wa=*(const float4*)wp;
      float4 wb=*(const float4*)(wp+4);
      acc[0][0]=__builtin_fmaf(x0,wa.x,acc[0][0]);
      acc[0][1]=__builtin_fmaf(x0,wa.y,acc[0][1]);
      acc[0][2]=__builtin_fmaf(x0,wa.z,acc[0][2]);
      acc[0][3]=__builtin_fmaf(x0,wa.w,acc[0][3]);
      acc[0][4]=__builtin_fmaf(x0,wb.x,acc[0][4]);
      acc[0][5]=__builtin_fmaf(x0,wb.y,acc[0][5]);
      acc[0][6]=__builtin_fmaf(x0,wb.z,acc[0][6]);
      acc[0][7]=__builtin_fmaf(x0,wb.w,acc[0][7]);
      acc[1][0]=__builtin_fmaf(x1,wa.x,acc[1][0]);
      acc[1][1]=__builtin_fmaf(x1,wa.y,acc[1][1]);
      acc[1][2]=__builtin_fmaf(x1,wa.z,acc[1][2]);
      acc[1][3]=__builtin_fmaf(x1,wa.w,acc[1][3]);
      acc[1][4]=__builtin_fmaf(x1,wb.x,acc[1][4]);
      acc[1][5]=__builtin_fmaf(x1,wb.y,acc[1][5]);
      acc[1][6]=__builtin_fmaf(x1,wb.z,acc[1][6]);
      acc[1][7]=__builtin_fmaf(x1,wb.w,acc[1][7]);
    }
  }
#pragma unroll
  for (int j=0;j<8;j++){
    int o=h0+j;
    float2 we=*(const float2*)(Wout + (size_t)o*GEO_MID_ + 128);
#pragma unroll
    for (int a=0;a<2;a++){
      float v=acc[a][j];
      v=__builtin_fmaf(-1.f, we.x, v);
      v=__builtin_fmaf(ssv[2*gsub+a], we.y, v);
      xout[(size_t)(g0+2*gsub+a)*256 + o]=v;
    }
  }
}

// ---------------------------------------------------------------- FEAT fused
// (unchanged, proven)
__global__ __launch_bounds__(256) void feat_kernel(
    const float* __restrict__ feats, const u16t* __restrict__ gidx16,
    const float* __restrict__ W1, const float* __restrict__ b1,
    const float* __restrict__ Wout, const float* __restrict__ bout,
    float* __restrict__ xout)
{
  __shared__ float smem[12800];                      // 51.2 KB
  float (*Xs)[68]  = (float(*)[68])smem;             // [64][68]
  float (*Ws)[128] = (float(*)[128])(smem + 64*68);  // [64][128]
  float (*Hs)[68]  = (float(*)[68])smem;             // [128][68] alias (post K-loop)
  float (*WoS)[128]= (float(*)[128])(smem + 128*68); // [32][128]
  const int t=threadIdx.x;
  const int g0=blockIdx.x*64;
  const int gsub=t>>4;
  const int h0=(t&15)*8;
  const int glx=t>>2, fq=(t&3)*16;
  const int hw=t>>1, fw0=(t&1)*32;
  const int fw1=(t&1)*16;
  const int gld=g0+glx, bld=gld>>10;
  float acc[4][8];
#pragma unroll
  for (int a=0;a<4;a++)
#pragma unroll
    for (int j=0;j<8;j++) acc[a][j]=0.f;

  for (int kk=0;kk<K_;kk++){
    int nidx=gidx16[gld*K_+kk];
    const float* fr=feats + ((size_t)bld*N_+(size_t)nidx)*FEAT_ + fq;
    float4 p[4];
#pragma unroll
    for (int e=0;e<4;e++) p[e]=((const float4*)fr)[e];
    const float* wr=W1 + (size_t)hw*FEAT_IN_ + kk*64 + fw0;
    float4 wv[8];
#pragma unroll
    for (int e=0;e<8;e++) wv[e]=((const float4*)wr)[e];
#pragma unroll
    for (int e=0;e<4;e++){
      Xs[fq+4*e+0][glx]=p[e].x;
      Xs[fq+4*e+1][glx]=p[e].y;
      Xs[fq+4*e+2][glx]=p[e].z;
      Xs[fq+4*e+3][glx]=p[e].w;
    }
#pragma unroll
    for (int e=0;e<8;e++){
      Ws[fw0+4*e+0][hw]=wv[e].x;
      Ws[fw0+4*e+1][hw]=wv[e].y;
      Ws[fw0+4*e+2][hw]=wv[e].z;
      Ws[fw0+4*e+3][hw]=wv[e].w;
    }
    __syncthreads();
#pragma unroll 4
    for (int k2=0;k2<64;k2++){
      float4 xv=*(const float4*)&Xs[k2][4*gsub];
      const float* wp=&Ws[k2][h0];
      float4 wa=*(const float4*)wp;
      float4 wb=*(const float4*)(wp+4);
      float xr[4]={xv.x,xv.y,xv.z,xv.w};
      float wf[8]={wa.x,wa.y,wa.z,wa.w,wb.x,wb.y,wb.z,wb.w};
#pragma unroll
      for (int a=0;a<4;a++)
#pragma unroll
        for (int j=0;j<8;j++)
          acc[a][j]=__builtin_fmaf(xr[a],wf[j],acc[a][j]);
    }
    __syncthreads();
  }
#pragma unroll
  for (int j=0;j<8;j++){
    float bv=b1[h0+j];
#pragma unroll
    for (int a=0;a<4;a++)
      Hs[h0+j][4*gsub+a]=fmaxf(__fadd_rn(acc[a][j],bv),0.f);
  }
  float ac2[4][8];
#pragma unroll
  for (int a=0;a<4;a++)
#pragma unroll
    for (int j=0;j<8;j++) ac2[a][j]=0.f;
  for (int c=0;c<4;c++){
    const float* wr2=Wout + (size_t)hw*H_ + c*32 + fw1;
    float4 w2[4];
#pragma unroll
    for (int e=0;e<4;e++) w2[e]=((const float4*)wr2)[e];
    __syncthreads();
#pragma unroll
    for (int e=0;e<4;e++){
      WoS[fw1+4*e+0][hw]=w2[e].x;
      WoS[fw1+4*e+1][hw]=w2[e].y;
      WoS[fw1+4*e+2][hw]=w2[e].z;
      WoS[fw1+4*e+3][hw]=w2[e].w;
    }
    __syncthreads();
#pragma unroll 4
    for (int k2=0;k2<32;k2++){
      float4 xv=*(const float4*)&Hs[c*32+k2][4*gsub];
      const float* wp=&WoS[k2][h0];
      float4 wa=*(const float4*)wp;
      float4 wb=*(const float4*)(wp+4);
      float xr[4]={xv.x,xv.y,xv.z,xv.w};
      float wf[8]={wa.x,wa.y,wa.z,wa.w,wb.x,wb.y,wb.z,wb.w};
#pragma unroll
      for (int a=0;a<4;a++)
#pragma unroll
        for (int j=0;j<8;j++)
          ac2[a][j]=__builtin_fmaf(xr[a],wf[j],ac2[a][j]);
    }
  }
#pragma unroll
  for (int j=0;j<8;j++){
    float bv=bout[h0+j];
#pragma unroll
    for (int a=0;a<4;a++)
      xout[(size_t)(g0+4*gsub+a)*256+128+h0+j]=__fadd_rn(ac2[a][j],bv);
  }
}

// ----------------------------------------------------------------
extern "C" void kernel_launch(void* const* d_in, const int* in_sizes, int n_in,
                              void* d_out, int out_size, void* d_ws, size_t ws_size,
                              hipStream_t stream) {
  const float* xyz  =(const float*)d_in[0];
  const float* feats=(const float*)d_in[1];
  const float* gW1  =(const float*)d_in[2];
  const float* gWout=(const float*)d_in[3];
  const float* fW1  =(const float*)d_in[4];
  const float* fb1  =(const float*)d_in[5];
  const float* fWout=(const float*)d_in[6];
  const float* fbout=(const float*)d_in[7];
  float* out=(float*)d_out;

  u16t* gidx16=(u16t*)d_ws;          // 1 MB
  float* xout = out + (size_t)B_*M_*3;

  fps_kernel <<<dim3(B_),          dim3(256), 0, stream>>>(xyz, out);
  knn_kernel <<<dim3((B_*M_)/4),   dim3(256), 0, stream>>>(xyz, out, gidx16);
  geo_kernel <<<dim3((B_*M_)/32),  dim3(256), 0, stream>>>(xyz, out, gidx16, gW1, gWout, xout);
  feat_kernel<<<dim3((B_*M_)/64),  dim3(256), 0, stream>>>(feats, gidx16, fW1, fb1, fWout, fbout, xout);
}

// Round 10
// 1500.185 us; speedup vs baseline: 1.4348x; 1.4348x over previous
//
#include <hip/hip_runtime.h>
#include <float.h>

#pragma clang fp contract(off)

#define B_ 16
#define N_ 4096
#define M_ 1024
#define K_ 32
#define FEAT_ 64
#define H_ 128
#define GEO_IN_ 160
#define GEO_MID_ 130
#define FEAT_IN_ 2048

typedef unsigned short u16t;

// ---- wave64 reductions in the VALU pipe (DPP), identity-preserving ----
#define DPP_STEP_MAX(ctrl) \
  t=(unsigned)__builtin_amdgcn_update_dpp((int)v,(int)v,(ctrl),0xf,0xf,false); \
  v=(t>v)?t:v;
#define DPP_STEP_MIN(ctrl) \
  t=(unsigned)__builtin_amdgcn_update_dpp((int)v,(int)v,(ctrl),0xf,0xf,false); \
  v=(t<v)?t:v;

__device__ __forceinline__ unsigned wave_max_u32(unsigned v){
  unsigned t;
  DPP_STEP_MAX(0x111) DPP_STEP_MAX(0x112) DPP_STEP_MAX(0x114) DPP_STEP_MAX(0x118)
  DPP_STEP_MAX(0x142) DPP_STEP_MAX(0x143)
  return (unsigned)__builtin_amdgcn_readlane((int)v,63);
}
__device__ __forceinline__ unsigned wave_min_u32(unsigned v){
  unsigned t;
  DPP_STEP_MIN(0x111) DPP_STEP_MIN(0x112) DPP_STEP_MIN(0x114) DPP_STEP_MIN(0x118)
  DPP_STEP_MIN(0x142) DPP_STEP_MIN(0x143)
  return (unsigned)__builtin_amdgcn_readlane((int)v,63);
}

// ---------------------------------------------------------------- FPS
// Proven 256-thread structure (4 waves, 1/SIMD; scalar float[16] arrays ->
// movrel, NO vector arrays: r7 proved f32x2 PX[bp] dynamic index => scratch
// (VGPR 80->76, 31.7ms cold dispatch, 2.1x slower steady)). Two selection
// micro-opts vs proven, both register-layout-neutral:
//  (a) tree argmax: m[16] then left-biased 15-node tournament (depth 4 vs
//      16-deep serial chain); left-wins-ties == first-max == sequential scan.
//  (b) ballot shortcut: unique-max lane (common) -> readlane(bi, ctz(mask));
//      exact DPP min-index fallback on cross-lane distance ties (primitive
//      combination HW-verified in r6/r7 runs).
// Publish/merge byte-proven: owner lane writes u64 key + float4 coords;
// 4-way tournament reads keys and coords in parallel.
__global__ __launch_bounds__(256) void fps_kernel(
    const float* __restrict__ xyz, float* __restrict__ outc)
{
  const int b = blockIdx.x, tid = threadIdx.x;
  const int wv = tid >> 6;
  const float* xb = xyz + (size_t)b * (N_*3);
  __shared__ unsigned long long kkey[2][4];
  __shared__ __align__(16) float4 kxyz[2][4];
  __shared__ float clist[M_][3];          // 12 KB
  float px[16], py[16], pz[16], dd[16];
#pragma unroll
  for (int j=0;j<16;j++){
    int i = tid + 256*j;
    px[j]=xb[i*3]; py[j]=xb[i*3+1]; pz[j]=xb[i*3+2];
    dd[j]=FLT_MAX;
  }
  float lx=xb[0], ly=xb[1], lz=xb[2];
  if (tid==0){ clist[0][0]=lx; clist[0][1]=ly; clist[0][2]=lz; }
  for (int t=1;t<M_;t++){
    // dist update: EXACT proven _rn sequence; results into m[16]
    float m[16];
#pragma unroll
    for (int j=0;j<16;j++){
      float dx=__fsub_rn(px[j],lx), dy=__fsub_rn(py[j],ly), dz=__fsub_rn(pz[j],lz);
      float d=__fadd_rn(__fadd_rn(__fmul_rn(dx,dx),__fmul_rn(dy,dy)),__fmul_rn(dz,dz));
      d=fminf(dd[j],d); dd[j]=d; m[j]=d;
    }
    // left-biased tournament argmax (right wins only on strict >):
    // == first-occurrence max of sequential scan, depth 4 not 16
    float v8[8]; int i8[8];
#pragma unroll
    for (int k=0;k<8;k++){
      bool r = m[2*k+1] > m[2*k];
      v8[k] = r ? m[2*k+1] : m[2*k];
      i8[k] = r ? 2*k+1    : 2*k;
    }
    float v4[4]; int i4[4];
#pragma unroll
    for (int k=0;k<4;k++){
      bool r = v8[2*k+1] > v8[2*k];
      v4[k] = r ? v8[2*k+1] : v8[2*k];
      i4[k] = r ? i8[2*k+1] : i8[2*k];
    }
    float v2[2]; int i2[2];
#pragma unroll
    for (int k=0;k<2;k++){
      bool r = v4[2*k+1] > v4[2*k];
      v2[k] = r ? v4[2*k+1] : v4[2*k];
      i2[k] = r ? i4[2*k+1] : i4[2*k];
    }
    bool rr = v2[1] > v2[0];
    float bd = rr ? v2[1] : v2[0];
    int   bj = rr ? i2[1] : i2[0];
    int   bi = tid + 256*bj;

    unsigned db=__float_as_uint(bd);          // bd>=0 => raw bits order-monotone
    unsigned smax=wave_max_u32(db);
    unsigned long long mask=__ballot(db==smax);
    unsigned sbi;
    if (mask & (mask-1)){                     // rare: cross-lane dist tie
      unsigned cand=(db==smax)?(unsigned)bi:0x7FFFFFFFu;
      sbi=wave_min_u32(cand);
    } else {                                  // unique winner lane (common)
      sbi=(unsigned)__builtin_amdgcn_readlane(bi,(int)__builtin_ctzll(mask));
    }
    // owner lane (sbi&255 == tid, always within this wave) publishes key+coords
    if ((unsigned)tid==(sbi&255u)){
      int oj=(int)(sbi>>8);
      kkey[t&1][wv]=((unsigned long long)smax<<32)|(unsigned)(0xFFFFFFFFu-sbi);
      kxyz[t&1][wv]=make_float4(px[oj],py[oj],pz[oj],0.f);
    }
    __syncthreads();
    // merge 4 wave candidates: higher dist wins, tie -> smaller index
    const unsigned long long* kp=kkey[t&1];
    const float4* cp=kxyz[t&1];
    unsigned long long k0=kp[0],k1=kp[1],k2=kp[2],k3=kp[3];
    float4 c0=cp[0],c1=cp[1],c2=cp[2],c3=cp[3];
    if (k1>k0){ k0=k1; c0=c1; }
    if (k3>k2){ k2=k3; c2=c3; }
    if (k2>k0){ k0=k2; c0=c2; }
    lx=c0.x; ly=c0.y; lz=c0.z;
    if (tid==0){ clist[t][0]=lx; clist[t][1]=ly; clist[t][2]=lz; }
  }
  __syncthreads();
  // bulk centroid write (one global pass, off the critical loop)
  for (int e=tid; e<M_; e+=256){
    size_t cb=((size_t)b*M_+(size_t)e)*3;
    outc[cb]=clist[e][0]; outc[cb+1]=clist[e][1]; outc[cb+2]=clist[e][2];
  }
}

// ---------------------------------------------------------------- KNN
// PROVEN version (byte-for-byte). One wave per centroid. 64 dists/lane in
// registers. Selection: 2x u32 DPP (min dist, then min idx among ties).
// Owner-lane rescan as exclusion + fminf min-tree + descending first-match
// index pass (same min value and smallest-index tie-break as sequential).
__global__ __launch_bounds__(256) void knn_kernel(
    const float* __restrict__ xyz, const float* __restrict__ outc,
    u16t* __restrict__ gidx16)
{
  const int w = blockIdx.x*4 + (threadIdx.x>>6);
  const int lane = threadIdx.x & 63;
  const int b = w >> 10;
  const float* xb = xyz + (size_t)b*(N_*3);
  float cx=outc[(size_t)w*3], cy=outc[(size_t)w*3+1], cz=outc[(size_t)w*3+2];
  float c2=__fadd_rn(__fadd_rn(__fmul_rn(cx,cx),__fmul_rn(cy,cy)),__fmul_rn(cz,cz));
  float dl[64];
  float lv=FLT_MAX; int lj=0;
#pragma unroll
  for (int j=0;j<64;j++){
    int i = lane + 64*j;
    float xx=xb[i*3], xy=xb[i*3+1], xz=xb[i*3+2];
    float x2=__fadd_rn(__fadd_rn(__fmul_rn(xx,xx),__fmul_rn(xy,xy)),__fmul_rn(xz,xz));
    float dt=__fadd_rn(__fadd_rn(__fmul_rn(cx,xx),__fmul_rn(cy,xy)),__fmul_rn(cz,xz));
    float d=__fsub_rn(__fadd_rn(c2,x2),__fmul_rn(2.f,dt));
    dl[j]=d;
    if (d<lv){ lv=d; lj=j; }
  }
  const int wb = w*K_;
  for (int k=0;k<K_;k++){
    unsigned u=__float_as_uint(lv);
    u = (u&0x80000000u) ? ~u : (u|0x80000000u);   // order-preserving
    unsigned smin=wave_min_u32(u);
    unsigned cand=(u==smin)?(unsigned)(lane+64*lj):0xFFFFFFFFu;
    unsigned widx=wave_min_u32(cand);
    if (lane==0) gidx16[wb+k]=(u16t)widx;
    if ((widx & 63)==(unsigned)lane){
      int slot=(int)(widx>>6);
#pragma unroll
      for (int j=0;j<64;j++) dl[j]=(j==slot)?FLT_MAX:dl[j];
      float m01[32];
#pragma unroll
      for (int j=0;j<32;j++) m01[j]=fminf(dl[2*j],dl[2*j+1]);
#pragma unroll
      for (int j=0;j<16;j++) m01[j]=fminf(m01[2*j],m01[2*j+1]);
#pragma unroll
      for (int j=0;j<8;j++)  m01[j]=fminf(m01[2*j],m01[2*j+1]);
#pragma unroll
      for (int j=0;j<4;j++)  m01[j]=fminf(m01[2*j],m01[2*j+1]);
      float nv=fminf(fminf(m01[0],m01[1]),fminf(m01[2],m01[3]));
      int nj=63;
#pragma unroll
      for (int j=62;j>=0;j--) nj=(dl[j]==nv)?j:nj;
      lv=nv; lj=nj;
    }
  }
}

// ---------------------------------------------------------------- GEO fused (GEMM-style)
// (unchanged, proven)
__global__ __launch_bounds__(256) void geo_kernel(
    const float* __restrict__ xyz, const float* __restrict__ outc,
    const u16t* __restrict__ gidx16, const float* __restrict__ W1,
    const float* __restrict__ Wout, float* __restrict__ xout)
{
  __shared__ float smem[160*33 + 64*128 + 32];
  float (*Es)[33]  = (float(*)[33])smem;
  float (*Hs)[33]  = (float(*)[33])smem;
  float (*Ws)[128] = (float(*)[128])(smem + 160*33);
  float* ssv = smem + 160*33 + 64*128;

  const int t=threadIdx.x;
  const int g0=blockIdx.x*32;
  for (int p=t; p<1024; p+=256){
    int g=p>>5, kk=p&31;
    int gg=g0+g, b=gg>>10;
    int idx=gidx16[gg*K_+kk];
    const float* pt = xyz + ((size_t)b*N_+(size_t)idx)*3;
    const float* cc = outc + (size_t)gg*3;
    float dx=__fsub_rn(pt[0],cc[0]);
    float dy=__fsub_rn(pt[1],cc[1]);
    float dz=__fsub_rn(pt[2],cc[2]);
    float sq=__fadd_rn(__fadd_rn(__fmul_rn(dx,dx),__fmul_rn(dy,dy)),__fmul_rn(dz,dz));
    int r=5*kk;
    Es[r][g]=dx; Es[r+1][g]=dy; Es[r+2][g]=dz;
    Es[r+3][g]=-1.f; Es[r+4][g]=__fmul_rn(-0.5f,sq);
  }
  const int gsub=t>>4, hsub=t&15, h0=hsub*8;
  const int hw=t>>1;
  float acc[2][8];
#pragma unroll
  for (int a=0;a<2;a++)
#pragma unroll
    for (int j=0;j<8;j++) acc[a][j]=0.f;
  __syncthreads();

  for (int c=0;c<3;c++){
    int i0=c*64;
    if (c<2){
      int fw0=(t&1)*32;
      const float* wr = W1 + (size_t)hw*GEO_IN_ + i0 + fw0;
      float4 wv[8];
#pragma unroll
      for (int e=0;e<8;e++) wv[e]=((const float4*)wr)[e];
#pragma unroll
      for (int e=0;e<8;e++){
        Ws[fw0+4*e+0][hw]=wv[e].x;
        Ws[fw0+4*e+1][hw]=wv[e].y;
        Ws[fw0+4*e+2][hw]=wv[e].z;
        Ws[fw0+4*e+3][hw]=wv[e].w;
      }
    } else {
      int fw0=(t&1)*16;
      const float* wr = W1 + (size_t)hw*GEO_IN_ + 128 + fw0;
      float4 wv[4];
#pragma unroll
      for (int e=0;e<4;e++) wv[e]=((const float4*)wr)[e];
#pragma unroll
      for (int e=0;e<4;e++){
        Ws[fw0+4*e+0][hw]=wv[e].x;
        Ws[fw0+4*e+1][hw]=wv[e].y;
        Ws[fw0+4*e+2][hw]=wv[e].z;
        Ws[fw0+4*e+3][hw]=wv[e].w;
      }
    }
    __syncthreads();
    int len=(c==2)?32:64;
    for (int k2=0;k2<len;k2++){
      float x0=Es[i0+k2][2*gsub], x1=Es[i0+k2][2*gsub+1];
      const float* wp=&Ws[k2][h0];
      float4 wa=*(const float4*)wp;
      float4 wb=*(const float4*)(wp+4);
      acc[0][0]=__builtin_fmaf(x0,wa.x,acc[0][0]);
      acc[0][1]=__builtin_fmaf(x0,wa.y,acc[0][1]);
      acc[0][2]=__builtin_fmaf(x0,wa.z,acc[0][2]);
      acc[0][3]=__builtin_fmaf(x0,wa.w,acc[0][3]);
      acc[0][4]=__builtin_fmaf(x0,wb.x,acc[0][4]);
      acc[0][5]=__builtin_fmaf(x0,wb.y,acc[0][5]);
      acc[0][6]=__builtin_fmaf(x0,wb.z,acc[0][6]);
      acc[0][7]=__builtin_fmaf(x0,wb.w,acc[0][7]);
      acc[1][0]=__builtin_fmaf(x1,wa.x,acc[1][0]);
      acc[1][1]=__builtin_fmaf(x1,wa.y,acc[1][1]);
      acc[1][2]=__builtin_fmaf(x1,wa.z,acc[1][2]);
      acc[1][3]=__builtin_fmaf(x1,wa.w,acc[1][3]);
      acc[1][4]=__builtin_fmaf(x1,wb.x,acc[1][4]);
      acc[1][5]=__builtin_fmaf(x1,wb.y,acc[1][5]);
      acc[1][6]=__builtin_fmaf(x1,wb.z,acc[1][6]);
      acc[1][7]=__builtin_fmaf(x1,wb.w,acc[1][7]);
    }
    __syncthreads();
  }
#pragma unroll
  for (int a=0;a<2;a++)
#pragma unroll
    for (int j=0;j<8;j++)
      Hs[h0+j][2*gsub+a]=acc[a][j];
  __syncthreads();
  if (t<32){
    float ss=0.f;
    for (int h=0;h<H_;h++){ float v=Hs[h][t]; ss=__builtin_fmaf(v,v,ss); }
    ssv[t]=__fmul_rn(-0.5f,ss);
  }
#pragma unroll
  for (int a=0;a<2;a++)
#pragma unroll
    for (int j=0;j<8;j++) acc[a][j]=0.f;
  for (int c=0;c<2;c++){
    int i0=c*64;
    int fw0=(t&1)*32;
    const float* wr = Wout + (size_t)hw*GEO_MID_ + i0 + fw0;
    float2 wv2[16];
#pragma unroll
    for (int e=0;e<16;e++) wv2[e]=((const float2*)wr)[e];
    __syncthreads();
#pragma unroll
    for (int e=0;e<16;e++){
      Ws[fw0+2*e+0][hw]=wv2[e].x;
      Ws[fw0+2*e+1][hw]=wv2[e].y;
    }
    __syncthreads();
    for (int k2=0;k2<64;k2++){
      float x0=Hs[i0+k2][2*gsub], x1=Hs[i0+k2][2*gsub+1];
      const float* wp=&Ws[k2][h0];
      float4 wa=*(const float4*)wp;
      float4 wb=*(const float4*)(wp+4);
      acc[0][0]=__builtin_fmaf(x0,wa.x,acc[0][0]);
      acc[0][1]=__builtin_fmaf(x0,wa.y,acc[0][1]);
      acc[0][2]=__builtin_fmaf(x0,wa.z,acc[0][2]);
      acc[0][3]=__builtin_fmaf(x0,wa.w,acc[0][3]);
      acc[0][4]=__builtin_fmaf(x0,wb.x,acc[0][4]);
      acc[0][5]=__builtin_fmaf(x0,wb.y,acc[0][5]);
      acc[0][6]=__builtin_fmaf(x0,wb.z,acc[0][6]);
      acc[0][7]=__builtin_fmaf(x0,wb.w,acc[0][7]);
      acc[1][0]=__builtin_fmaf(x1,wa.x,acc[1][0]);
      acc[1][1]=__builtin_fmaf(x1,wa.y,acc[1][1]);
      acc[1][2]=__builtin_fmaf(x1,wa.z,acc[1][2]);
      acc[1][3]=__builtin_fmaf(x1,wa.w,acc[1][3]);
      acc[1][4]=__builtin_fmaf(x1,wb.x,acc[1][4]);
      acc[1][5]=__builtin_fmaf(x1,wb.y,acc[1][5]);
      acc[1][6]=__builtin_fmaf(x1,wb.z,acc[1][6]);
      acc[1][7]=__builtin_fmaf(x1,wb.w,acc[1][7]);
    }
  }
#pragma unroll
  for (int j=0;j<8;j++){
    int o=h0+j;
    float2 we=*(const float2*)(Wout + (size_t)o*GEO_MID_ + 128);
#pragma unroll
    for (int a=0;a<2;a++){
      float v=acc[a][j];
      v=__builtin_fmaf(-1.f, we.x, v);
      v=__builtin_fmaf(ssv[2*gsub+a], we.y, v);
      xout[(size_t)(g0+2*gsub+a)*256 + o]=v;
    }
  }
}

// ---------------------------------------------------------------- FEAT fused
// (unchanged, proven)
__global__ __launch_bounds__(256) void feat_kernel(
    const float* __restrict__ feats, const u16t* __restrict__ gidx16,
    const float* __restrict__ W1, const float* __restrict__ b1,
    const float* __restrict__ Wout, const float* __restrict__ bout,
    float* __restrict__ xout)
{
  __shared__ float smem[12800];                      // 51.2 KB
  float (*Xs)[68]  = (float(*)[68])smem;             // [64][68]
  float (*Ws)[128] = (float(*)[128])(smem + 64*68);  // [64][128]
  float (*Hs)[68]  = (float(*)[68])smem;             // [128][68] alias (post K-loop)
  float (*WoS)[128]= (float(*)[128])(smem + 128*68); // [32][128]
  const int t=threadIdx.x;
  const int g0=blockIdx.x*64;
  const int gsub=t>>4;
  const int h0=(t&15)*8;
  const int glx=t>>2, fq=(t&3)*16;
  const int hw=t>>1, fw0=(t&1)*32;
  const int fw1=(t&1)*16;
  const int gld=g0+glx, bld=gld>>10;
  float acc[4][8];
#pragma unroll
  for (int a=0;a<4;a++)
#pragma unroll
    for (int j=0;j<8;j++) acc[a][j]=0.f;

  for (int kk=0;kk<K_;kk++){
    int nidx=gidx16[gld*K_+kk];
    const float* fr=feats + ((size_t)bld*N_+(size_t)nidx)*FEAT_ + fq;
    float4 p[4];
#pragma unroll
    for (int e=0;e<4;e++) p[e]=((const float4*)fr)[e];
    const float* wr=W1 + (size_t)hw*FEAT_IN_ + kk*64 + fw0;
    float4 wv[8];
#pragma unroll
    for (int e=0;e<8;e++) wv[e]=((const float4*)wr)[e];
#pragma unroll
    for (int e=0;e<4;e++){
      Xs[fq+4*e+0][glx]=p[e].x;
      Xs[fq+4*e+1][glx]=p[e].y;
      Xs[fq+4*e+2][glx]=p[e].z;
      Xs[fq+4*e+3][glx]=p[e].w;
    }
#pragma unroll
    for (int e=0;e<8;e++){
      Ws[fw0+4*e+0][hw]=wv[e].x;
      Ws[fw0+4*e+1][hw]=wv[e].y;
      Ws[fw0+4*e+2][hw]=wv[e].z;
      Ws[fw0+4*e+3][hw]=wv[e].w;
    }
    __syncthreads();
#pragma unroll 4
    for (int k2=0;k2<64;k2++){
      float4 xv=*(const float4*)&Xs[k2][4*gsub];
      const float* wp=&Ws[k2][h0];
      float4 wa=*(const float4*)wp;
      float4 wb=*(const float4*)(wp+4);
      float xr[4]={xv.x,xv.y,xv.z,xv.w};
      float wf[8]={wa.x,wa.y,wa.z,wa.w,wb.x,wb.y,wb.z,wb.w};
#pragma unroll
      for (int a=0;a<4;a++)
#pragma unroll
        for (int j=0;j<8;j++)
          acc[a][j]=__builtin_fmaf(xr[a],wf[j],acc[a][j]);
    }
    __syncthreads();
  }
#pragma unroll
  for (int j=0;j<8;j++){
    float bv=b1[h0+j];
#pragma unroll
    for (int a=0;a<4;a++)
      Hs[h0+j][4*gsub+a]=fmaxf(__fadd_rn(acc[a][j],bv),0.f);
  }
  float ac2[4][8];
#pragma unroll
  for (int a=0;a<4;a++)
#pragma unroll
    for (int j=0;j<8;j++) ac2[a][j]=0.f;
  for (int c=0;c<4;c++){
    const float* wr2=Wout + (size_t)hw*H_ + c*32 + fw1;
    float4 w2[4];
#pragma unroll
    for (int e=0;e<4;e++) w2[e]=((const float4*)wr2)[e];
    __syncthreads();
#pragma unroll
    for (int e=0;e<4;e++){
      WoS[fw1+4*e+0][hw]=w2[e].x;
      WoS[fw1+4*e+1][hw]=w2[e].y;
      WoS[fw1+4*e+2][hw]=w2[e].z;
      WoS[fw1+4*e+3][hw]=w2[e].w;
    }
    __syncthreads();
#pragma unroll 4
    for (int k2=0;k2<32;k2++){
      float4 xv=*(const float4*)&Hs[c*32+k2][4*gsub];
      const float* wp=&WoS[k2][h0];
      float4 wa=*(const float4*)wp;
      float4 wb=*(const float4*)(wp+4);
      float xr[4]={xv.x,xv.y,xv.z,xv.w};
      float wf[8]={wa.x,wa.y,wa.z,wa.w,wb.x,wb.y,wb.z,wb.w};
#pragma unroll
      for (int a=0;a<4;a++)
#pragma unroll
        for (int j=0;j<8;j++)
          ac2[a][j]=__builtin_fmaf(xr[a],wf[j],ac2[a][j]);
    }
  }
#pragma unroll
  for (int j=0;j<8;j++){
    float bv=bout[h0+j];
#pragma unroll
    for (int a=0;a<4;a++)
      xout[(size_t)(g0+4*gsub+a)*256+128+h0+j]=__fadd_rn(ac2[a][j],bv);
  }
}

// ----------------------------------------------------------------
extern "C" void kernel_launch(void* const* d_in, const int* in_sizes, int n_in,
                              void* d_out, int out_size, void* d_ws, size_t ws_size,
                              hipStream_t stream) {
  const float* xyz  =(const float*)d_in[0];
  const float* feats=(const float*)d_in[1];
  const float* gW1  =(const float*)d_in[2];
  const float* gWout=(const float*)d_in[3];
  const float* fW1  =(const float*)d_in[4];
  const float* fb1  =(const float*)d_in[5];
  const float* fWout=(const float*)d_in[6];
  const float* fbout=(const float*)d_in[7];
  float* out=(float*)d_out;

  u16t* gidx16=(u16t*)d_ws;          // 1 MB
  float* xout = out + (size_t)B_*M_*3;

  fps_kernel <<<dim3(B_),          dim3(256), 0, stream>>>(xyz, out);
  knn_kernel <<<dim3((B_*M_)/4),   dim3(256), 0, stream>>>(xyz, out, gidx16);
  geo_kernel <<<dim3((B_*M_)/32),  dim3(256), 0, stream>>>(xyz, out, gidx16, gW1, gWout, xout);
  feat_kernel<<<dim3((B_*M_)/64),  dim3(256), 0, stream>>>(feats, gidx16, fW1, fb1, fWout, fbout, xout);
}

// Round 11
// 1134.900 us; speedup vs baseline: 1.8967x; 1.3219x over previous
//
#include <hip/hip_runtime.h>
#include <float.h>

#pragma clang fp contract(off)

#define B_ 16
#define N_ 4096
#define M_ 1024
#define K_ 32
#define FEAT_ 64
#define H_ 128
#define GEO_IN_ 160
#define GEO_MID_ 130
#define FEAT_IN_ 2048

typedef unsigned short u16t;

// ---- wave64 reductions in the VALU pipe (DPP), identity-preserving ----
#define DPP_STEP_MAX(ctrl) \
  t=(unsigned)__builtin_amdgcn_update_dpp((int)v,(int)v,(ctrl),0xf,0xf,false); \
  v=(t>v)?t:v;
#define DPP_STEP_MIN(ctrl) \
  t=(unsigned)__builtin_amdgcn_update_dpp((int)v,(int)v,(ctrl),0xf,0xf,false); \
  v=(t<v)?t:v;

__device__ __forceinline__ unsigned wave_max_u32(unsigned v){
  unsigned t;
  DPP_STEP_MAX(0x111) DPP_STEP_MAX(0x112) DPP_STEP_MAX(0x114) DPP_STEP_MAX(0x118)
  DPP_STEP_MAX(0x142) DPP_STEP_MAX(0x143)
  return (unsigned)__builtin_amdgcn_readlane((int)v,63);
}
__device__ __forceinline__ unsigned wave_min_u32(unsigned v){
  unsigned t;
  DPP_STEP_MIN(0x111) DPP_STEP_MIN(0x112) DPP_STEP_MIN(0x114) DPP_STEP_MIN(0x118)
  DPP_STEP_MIN(0x142) DPP_STEP_MIN(0x143)
  return (unsigned)__builtin_amdgcn_readlane((int)v,63);
}

// ---------------------------------------------------------------- FPS
// PROVEN 703us version, byte-exact revert. Two-strike verdict on selection
// micro-opts: r10 tree+ballot = 872us, r6 512-thr = 784us — the serial
// argmax chain + always-2-phase DPP is the local optimum for this structure.
__global__ __launch_bounds__(256) void fps_kernel(
    const float* __restrict__ xyz, float* __restrict__ outc)
{
  const int b = blockIdx.x, tid = threadIdx.x;
  const int wv = tid >> 6;
  const float* xb = xyz + (size_t)b * (N_*3);
  __shared__ unsigned long long kkey[2][4];
  __shared__ __align__(16) float4 kxyz[2][4];
  __shared__ float clist[M_][3];          // 12 KB
  float px[16], py[16], pz[16], dd[16];
#pragma unroll
  for (int j=0;j<16;j++){
    int i = tid + 256*j;
    px[j]=xb[i*3]; py[j]=xb[i*3+1]; pz[j]=xb[i*3+2];
    dd[j]=FLT_MAX;
  }
  float lx=xb[0], ly=xb[1], lz=xb[2];
  if (tid==0){ clist[0][0]=lx; clist[0][1]=ly; clist[0][2]=lz; }
  for (int t=1;t<M_;t++){
    float bd=-FLT_MAX; int bi=0;
#pragma unroll
    for (int j=0;j<16;j++){
      float dx=__fsub_rn(px[j],lx), dy=__fsub_rn(py[j],ly), dz=__fsub_rn(pz[j],lz);
      float d=__fadd_rn(__fadd_rn(__fmul_rn(dx,dx),__fmul_rn(dy,dy)),__fmul_rn(dz,dz));
      d=fminf(dd[j],d); dd[j]=d;
      if (d>bd){ bd=d; bi=tid+256*j; }   // j asc => idx asc; strict > keeps first max
    }
    unsigned db=__float_as_uint(bd);          // bd>=0 => raw bits order-monotone
    unsigned smax=wave_max_u32(db);
    unsigned cand=(db==smax)?(unsigned)bi:0x7FFFFFFFu;
    unsigned sbi=wave_min_u32(cand);
    // owner lane (bi&255 == tid, always within this wave) publishes key+coords
    if ((unsigned)tid==(sbi&255u)){
      int oj=(int)(sbi>>8);
      kkey[t&1][wv]=((unsigned long long)smax<<32)|(unsigned)(0xFFFFFFFFu-sbi);
      kxyz[t&1][wv]=make_float4(px[oj],py[oj],pz[oj],0.f);
    }
    __syncthreads();
    // merge 4 wave candidates: higher dist wins, tie -> smaller index
    const unsigned long long* kp=kkey[t&1];
    const float4* cp=kxyz[t&1];
    unsigned long long k0=kp[0],k1=kp[1],k2=kp[2],k3=kp[3];
    float4 c0=cp[0],c1=cp[1],c2=cp[2],c3=cp[3];
    if (k1>k0){ k0=k1; c0=c1; }
    if (k3>k2){ k2=k3; c2=c3; }
    if (k2>k0){ k0=k2; c0=c2; }
    lx=c0.x; ly=c0.y; lz=c0.z;
    if (tid==0){ clist[t][0]=lx; clist[t][1]=ly; clist[t][2]=lz; }
  }
  __syncthreads();
  // bulk centroid write (one global pass, off the critical loop)
  for (int e=tid; e<M_; e+=256){
    size_t cb=((size_t)b*M_+(size_t)e)*3;
    outc[cb]=clist[e][0]; outc[cb+1]=clist[e][1]; outc[cb+2]=clist[e][2];
  }
}

// ---------------------------------------------------------------- KNN
// Wave-parallel-refill version. One wave per centroid (wave-uniform c).
// Per lane: only (lv,lj) head + 64-bit cons mask of consumed slots — NO
// dl[64] array. Selection (unchanged, proven): 2-phase DPP (min dist, then
// min global idx among ties). Refill after each pop is WAVE-PARALLEL and
// STATELESS: lane s recomputes the owner's slot-s distance from xb with the
// EXACT same _rn op sequence as the init scan (deterministic FP => identical
// bits), masks consumed slots to 0xFFFFFFFF (beaten by any real transformed
// value; transform(FLT_MAX)=0xFF7FFFFF<0xFFFFFFFF), then 2-phase DPP min
// gives (min dist over unconsumed, smallest slot attaining) == the proven
// sequential rescan's exclusion+min+smallest-index semantics exactly.
// No sorted-list invariants; ~60 wave-ops/round vs ~310 (owner rescan was
// ~70% of KNN issue, executed 1-lane-active but full-wave cost).
__global__ __launch_bounds__(256) void knn_kernel(
    const float* __restrict__ xyz, const float* __restrict__ outc,
    u16t* __restrict__ gidx16)
{
  const int w = blockIdx.x*4 + (threadIdx.x>>6);
  const int lane = threadIdx.x & 63;
  const int b = w >> 10;
  const float* xb = xyz + (size_t)b*(N_*3);
  float cx=outc[(size_t)w*3], cy=outc[(size_t)w*3+1], cz=outc[(size_t)w*3+2];
  float c2=__fadd_rn(__fadd_rn(__fmul_rn(cx,cx),__fmul_rn(cy,cy)),__fmul_rn(cz,cz));

  float lv=FLT_MAX; int lj=0;
#pragma unroll
  for (int j=0;j<64;j++){
    int i = lane + 64*j;
    float xx=xb[i*3], xy=xb[i*3+1], xz=xb[i*3+2];
    float x2=__fadd_rn(__fadd_rn(__fmul_rn(xx,xx),__fmul_rn(xy,xy)),__fmul_rn(xz,xz));
    float dt=__fadd_rn(__fadd_rn(__fmul_rn(cx,xx),__fmul_rn(cy,xy)),__fmul_rn(cz,xz));
    float d=__fsub_rn(__fadd_rn(c2,x2),__fmul_rn(2.f,dt));
    if (d<lv){ lv=d; lj=j; }               // strict <: smallest j attaining min
  }
  unsigned long long cons = 0ull;          // my consumed slots
  const int wb = w*K_;
  for (int k=0;k<K_;k++){
    unsigned u=__float_as_uint(lv);
    u = (u&0x80000000u) ? ~u : (u|0x80000000u);   // order-preserving transform
    unsigned smin=wave_min_u32(u);
    unsigned cand=(u==smin)?(unsigned)(lane+64*lj):0xFFFFFFFFu;
    unsigned widx=wave_min_u32(cand);
    if (lane==0) gidx16[wb+k]=(u16t)widx;
    int owner=(int)(widx & 63u);
    int slot =(int)(widx >> 6);
    if (lane==owner) cons |= (1ull<<(unsigned)slot);
    if (k==K_-1) break;                    // nothing consumes the last refill
    // broadcast owner's consumed mask (owner is wave-uniform)
    unsigned clo=(unsigned)__builtin_amdgcn_readlane((int)(unsigned)cons, owner);
    unsigned chi=(unsigned)__builtin_amdgcn_readlane((int)(unsigned)(cons>>32), owner);
    unsigned long long ocons=((unsigned long long)chi<<32)|(unsigned long long)clo;
    // wave-parallel refill: lane s recomputes owner's slot s (bit-exact)
    int ip = owner + 64*lane;
    float xx=xb[ip*3], xy=xb[ip*3+1], xz=xb[ip*3+2];
    float x2=__fadd_rn(__fadd_rn(__fmul_rn(xx,xx),__fmul_rn(xy,xy)),__fmul_rn(xz,xz));
    float dt=__fadd_rn(__fadd_rn(__fmul_rn(cx,xx),__fmul_rn(cy,xy)),__fmul_rn(cz,xz));
    float d=__fsub_rn(__fadd_rn(c2,x2),__fmul_rn(2.f,dt));
    unsigned uj=__float_as_uint(d);
    uj=(uj&0x80000000u)?~uj:(uj|0x80000000u);
    if ((ocons>>(unsigned)lane)&1ull) uj=0xFFFFFFFFu;   // exclude consumed
    unsigned smin2=wave_min_u32(uj);
    unsigned cs=(uj==smin2)?(unsigned)lane:64u;
    unsigned sslot=wave_min_u32(cs);                    // smallest slot at min
    float dnew=__uint_as_float((unsigned)__builtin_amdgcn_readlane(__float_as_int(d),(int)sslot));
    if (lane==owner){ lv=dnew; lj=(int)sslot; }
  }
}

// ---------------------------------------------------------------- GEO fused (GEMM-style)
// (unchanged, proven)
__global__ __launch_bounds__(256) void geo_kernel(
    const float* __restrict__ xyz, const float* __restrict__ outc,
    const u16t* __restrict__ gidx16, const float* __restrict__ W1,
    const float* __restrict__ Wout, float* __restrict__ xout)
{
  __shared__ float smem[160*33 + 64*128 + 32];
  float (*Es)[33]  = (float(*)[33])smem;
  float (*Hs)[33]  = (float(*)[33])smem;
  float (*Ws)[128] = (float(*)[128])(smem + 160*33);
  float* ssv = smem + 160*33 + 64*128;

  const int t=threadIdx.x;
  const int g0=blockIdx.x*32;
  for (int p=t; p<1024; p+=256){
    int g=p>>5, kk=p&31;
    int gg=g0+g, b=gg>>10;
    int idx=gidx16[gg*K_+kk];
    const float* pt = xyz + ((size_t)b*N_+(size_t)idx)*3;
    const float* cc = outc + (size_t)gg*3;
    float dx=__fsub_rn(pt[0],cc[0]);
    float dy=__fsub_rn(pt[1],cc[1]);
    float dz=__fsub_rn(pt[2],cc[2]);
    float sq=__fadd_rn(__fadd_rn(__fmul_rn(dx,dx),__fmul_rn(dy,dy)),__fmul_rn(dz,dz));
    int r=5*kk;
    Es[r][g]=dx; Es[r+1][g]=dy; Es[r+2][g]=dz;
    Es[r+3][g]=-1.f; Es[r+4][g]=__fmul_rn(-0.5f,sq);
  }
  const int gsub=t>>4, hsub=t&15, h0=hsub*8;
  const int hw=t>>1;
  float acc[2][8];
#pragma unroll
  for (int a=0;a<2;a++)
#pragma unroll
    for (int j=0;j<8;j++) acc[a][j]=0.f;
  __syncthreads();

  for (int c=0;c<3;c++){
    int i0=c*64;
    if (c<2){
      int fw0=(t&1)*32;
      const float* wr = W1 + (size_t)hw*GEO_IN_ + i0 + fw0;
      float4 wv[8];
#pragma unroll
      for (int e=0;e<8;e++) wv[e]=((const float4*)wr)[e];
#pragma unroll
      for (int e=0;e<8;e++){
        Ws[fw0+4*e+0][hw]=wv[e].x;
        Ws[fw0+4*e+1][hw]=wv[e].y;
        Ws[fw0+4*e+2][hw]=wv[e].z;
        Ws[fw0+4*e+3][hw]=wv[e].w;
      }
    } else {
      int fw0=(t&1)*16;
      const float* wr = W1 + (size_t)hw*GEO_IN_ + 128 + fw0;
      float4 wv[4];
#pragma unroll
      for (int e=0;e<4;e++) wv[e]=((const float4*)wr)[e];
#pragma unroll
      for (int e=0;e<4;e++){
        Ws[fw0+4*e+0][hw]=wv[e].x;
        Ws[fw0+4*e+1][hw]=wv[e].y;
        Ws[fw0+4*e+2][hw]=wv[e].z;
        Ws[fw0+4*e+3][hw]=wv[e].w;
      }
    }
    __syncthreads();
    int len=(c==2)?32:64;
    for (int k2=0;k2<len;k2++){
      float x0=Es[i0+k2][2*gsub], x1=Es[i0+k2][2*gsub+1];
      const float* wp=&Ws[k2][h0];
      float4 wa=*(const float4*)wp;
      float4 wb=*(const float4*)(wp+4);
      acc[0][0]=__builtin_fmaf(x0,wa.x,acc[0][0]);
      acc[0][1]=__builtin_fmaf(x0,wa.y,acc[0][1]);
      acc[0][2]=__builtin_fmaf(x0,wa.z,acc[0][2]);
      acc[0][3]=__builtin_fmaf(x0,wa.w,acc[0][3]);
      acc[0][4]=__builtin_fmaf(x0,wb.x,acc[0][4]);
      acc[0][5]=__builtin_fmaf(x0,wb.y,acc[0][5]);
      acc[0][6]=__builtin_fmaf(x0,wb.z,acc[0][6]);
      acc[0][7]=__builtin_fmaf(x0,wb.w,acc[0][7]);
      acc[1][0]=__builtin_fmaf(x1,wa.x,acc[1][0]);
      acc[1][1]=__builtin_fmaf(x1,wa.y,acc[1][1]);
      acc[1][2]=__builtin_fmaf(x1,wa.z,acc[1][2]);
      acc[1][3]=__builtin_fmaf(x1,wa.w,acc[1][3]);
      acc[1][4]=__builtin_fmaf(x1,wb.x,acc[1][4]);
      acc[1][5]=__builtin_fmaf(x1,wb.y,acc[1][5]);
      acc[1][6]=__builtin_fmaf(x1,wb.z,acc[1][6]);
      acc[1][7]=__builtin_fmaf(x1,wb.w,acc[1][7]);
    }
    __syncthreads();
  }
#pragma unroll
  for (int a=0;a<2;a++)
#pragma unroll
    for (int j=0;j<8;j++)
      Hs[h0+j][2*gsub+a]=acc[a][j];
  __syncthreads();
  if (t<32){
    float ss=0.f;
    for (int h=0;h<H_;h++){ float v=Hs[h][t]; ss=__builtin_fmaf(v,v,ss); }
    ssv[t]=__fmul_rn(-0.5f,ss);
  }
#pragma unroll
  for (int a=0;a<2;a++)
#pragma unroll
    for (int j=0;j<8;j++) acc[a][j]=0.f;
  for (int c=0;c<2;c++){
    int i0=c*64;
    int fw0=(t&1)*32;
    const float* wr = Wout + (size_t)hw*GEO_MID_ + i0 + fw0;
    float2 wv2[16];
#pragma unroll
    for (int e=0;e<16;e++) wv2[e]=((const float2*)wr)[e];
    __syncthreads();
#pragma unroll
    for (int e=0;e<16;e++){
      Ws[fw0+2*e+0][hw]=wv2[e].x;
      Ws[fw0+2*e+1][hw]=wv2[e].y;
    }
    __syncthreads();
    for (int k2=0;k2<64;k2++){
      float x0=Hs[i0+k2][2*gsub], x1=Hs[i0+k2][2*gsub+1];
      const float* wp=&Ws[k2][h0];
      float4 wa=*(const float4*)wp;
      float4 wb=*(const float4*)(wp+4);
      acc[0][0]=__builtin_fmaf(x0,wa.x,acc[0][0]);
      acc[0][1]=__builtin_fmaf(x0,wa.y,acc[0][1]);
      acc[0][2]=__builtin_fmaf(x0,wa.z,acc[0][2]);
      acc[0][3]=__builtin_fmaf(x0,wa.w,acc[0][3]);
      acc[0][4]=__builtin_fmaf(x0,wb.x,acc[0][4]);
      acc[0][5]=__builtin_fmaf(x0,wb.y,acc[0][5]);
      acc[0][6]=__builtin_fmaf(x0,wb.z,acc[0][6]);
      acc[0][7]=__builtin_fmaf(x0,wb.w,acc[0][7]);
      acc[1][0]=__builtin_fmaf(x1,wa.x,acc[1][0]);
      acc[1][1]=__builtin_fmaf(x1,wa.y,acc[1][1]);
      acc[1][2]=__builtin_fmaf(x1,wa.z,acc[1][2]);
      acc[1][3]=__builtin_fmaf(x1,wa.w,acc[1][3]);
      acc[1][4]=__builtin_fmaf(x1,wb.x,acc[1][4]);
      acc[1][5]=__builtin_fmaf(x1,wb.y,acc[1][5]);
      acc[1][6]=__builtin_fmaf(x1,wb.z,acc[1][6]);
      acc[1][7]=__builtin_fmaf(x1,wb.w,acc[1][7]);
    }
  }
#pragma unroll
  for (int j=0;j<8;j++){
    int o=h0+j;
    float2 we=*(const float2*)(Wout + (size_t)o*GEO_MID_ + 128);
#pragma unroll
    for (int a=0;a<2;a++){
      float v=acc[a][j];
      v=__builtin_fmaf(-1.f, we.x, v);
      v=__builtin_fmaf(ssv[2*gsub+a], we.y, v);
      xout[(size_t)(g0+2*gsub+a)*256 + o]=v;
    }
  }
}

// ---------------------------------------------------------------- FEAT fused
// (unchanged, proven)
__global__ __launch_bounds__(256) void feat_kernel(
    const float* __restrict__ feats, const u16t* __restrict__ gidx16,
    const float* __restrict__ W1, const float* __restrict__ b1,
    const float* __restrict__ Wout, const float* __restrict__ bout,
    float* __restrict__ xout)
{
  __shared__ float smem[12800];                      // 51.2 KB
  float (*Xs)[68]  = (float(*)[68])smem;             // [64][68]
  float (*Ws)[128] = (float(*)[128])(smem + 64*68);  // [64][128]
  float (*Hs)[68]  = (float(*)[68])smem;             // [128][68] alias (post K-loop)
  float (*WoS)[128]= (float(*)[128])(smem + 128*68); // [32][128]
  const int t=threadIdx.x;
  const int g0=blockIdx.x*64;
  const int gsub=t>>4;
  const int h0=(t&15)*8;
  const int glx=t>>2, fq=(t&3)*16;
  const int hw=t>>1, fw0=(t&1)*32;
  const int fw1=(t&1)*16;
  const int gld=g0+glx, bld=gld>>10;
  float acc[4][8];
#pragma unroll
  for (int a=0;a<4;a++)
#pragma unroll
    for (int j=0;j<8;j++) acc[a][j]=0.f;

  for (int kk=0;kk<K_;kk++){
    int nidx=gidx16[gld*K_+kk];
    const float* fr=feats + ((size_t)bld*N_+(size_t)nidx)*FEAT_ + fq;
    float4 p[4];
#pragma unroll
    for (int e=0;e<4;e++) p[e]=((const float4*)fr)[e];
    const float* wr=W1 + (size_t)hw*FEAT_IN_ + kk*64 + fw0;
    float4 wv[8];
#pragma unroll
    for (int e=0;e<8;e++) wv[e]=((const float4*)wr)[e];
#pragma unroll
    for (int e=0;e<4;e++){
      Xs[fq+4*e+0][glx]=p[e].x;
      Xs[fq+4*e+1][glx]=p[e].y;
      Xs[fq+4*e+2][glx]=p[e].z;
      Xs[fq+4*e+3][glx]=p[e].w;
    }
#pragma unroll
    for (int e=0;e<8;e++){
      Ws[fw0+4*e+0][hw]=wv[e].x;
      Ws[fw0+4*e+1][hw]=wv[e].y;
      Ws[fw0+4*e+2][hw]=wv[e].z;
      Ws[fw0+4*e+3][hw]=wv[e].w;
    }
    __syncthreads();
#pragma unroll 4
    for (int k2=0;k2<64;k2++){
      float4 xv=*(const float4*)&Xs[k2][4*gsub];
      const float* wp=&Ws[k2][h0];
      float4 wa=*(const float4*)wp;
      float4 wb=*(const float4*)(wp+4);
      float xr[4]={xv.x,xv.y,xv.z,xv.w};
      float wf[8]={wa.x,wa.y,wa.z,wa.w,wb.x,wb.y,wb.z,wb.w};
#pragma unroll
      for (int a=0;a<4;a++)
#pragma unroll
        for (int j=0;j<8;j++)
          acc[a][j]=__builtin_fmaf(xr[a],wf[j],acc[a][j]);
    }
    __syncthreads();
  }
#pragma unroll
  for (int j=0;j<8;j++){
    float bv=b1[h0+j];
#pragma unroll
    for (int a=0;a<4;a++)
      Hs[h0+j][4*gsub+a]=fmaxf(__fadd_rn(acc[a][j],bv),0.f);
  }
  float ac2[4][8];
#pragma unroll
  for (int a=0;a<4;a++)
#pragma unroll
    for (int j=0;j<8;j++) ac2[a][j]=0.f;
  for (int c=0;c<4;c++){
    const float* wr2=Wout + (size_t)hw*H_ + c*32 + fw1;
    float4 w2[4];
#pragma unroll
    for (int e=0;e<4;e++) w2[e]=((const float4*)wr2)[e];
    __syncthreads();
#pragma unroll
    for (int e=0;e<4;e++){
      WoS[fw1+4*e+0][hw]=w2[e].x;
      WoS[fw1+4*e+1][hw]=w2[e].y;
      WoS[fw1+4*e+2][hw]=w2[e].z;
      WoS[fw1+4*e+3][hw]=w2[e].w;
    }
    __syncthreads();
#pragma unroll 4
    for (int k2=0;k2<32;k2++){
      float4 xv=*(const float4*)&Hs[c*32+k2][4*gsub];
      const float* wp=&WoS[k2][h0];
      float4 wa=*(const float4*)wp;
      float4 wb=*(const float4*)(wp+4);
      float xr[4]={xv.x,xv.y,xv.z,xv.w};
      float wf[8]={wa.x,wa.y,wa.z,wa.w,wb.x,wb.y,wb.z,wb.w};
#pragma unroll
      for (int a=0;a<4;a++)
#pragma unroll
        for (int j=0;j<8;j++)
          ac2[a][j]=__builtin_fmaf(xr[a],wf[j],ac2[a][j]);
    }
  }
#pragma unroll
  for (int j=0;j<8;j++){
    float bv=bout[h0+j];
#pragma unroll
    for (int a=0;a<4;a++)
      xout[(size_t)(g0+4*gsub+a)*256+128+h0+j]=__fadd_rn(ac2[a][j],bv);
  }
}

// ----------------------------------------------------------------
extern "C" void kernel_launch(void* const* d_in, const int* in_sizes, int n_in,
                              void* d_out, int out_size, void* d_ws, size_t ws_size,
                              hipStream_t stream) {
  const float* xyz  =(const float*)d_in[0];
  const float* feats=(const float*)d_in[1];
  const float* gW1  =(const float*)d_in[2];
  const float* gWout=(const float*)d_in[3];
  const float* fW1  =(const float*)d_in[4];
  const float* fb1  =(const float*)d_in[5];
  const float* fWout=(const float*)d_in[6];
  const float* fbout=(const float*)d_in[7];
  float* out=(float*)d_out;

  u16t* gidx16=(u16t*)d_ws;          // 1 MB
  float* xout = out + (size_t)B_*M_*3;

  fps_kernel <<<dim3(B_),          dim3(256), 0, stream>>>(xyz, out);
  knn_kernel <<<dim3((B_*M_)/4),   dim3(256), 0, stream>>>(xyz, out, gidx16);
  geo_kernel <<<dim3((B_*M_)/32),  dim3(256), 0, stream>>>(xyz, out, gidx16, gW1, gWout, xout);
  feat_kernel<<<dim3((B_*M_)/64),  dim3(256), 0, stream>>>(feats, gidx16, fW1, fb1, fWout, fbout, xout);
}

// Round 12
// 1081.539 us; speedup vs baseline: 1.9902x; 1.0493x over previous
//
#include <hip/hip_runtime.h>
#include <float.h>

#pragma clang fp contract(off)

#define B_ 16
#define N_ 4096
#define M_ 1024
#define K_ 32
#define FEAT_ 64
#define H_ 128
#define GEO_IN_ 160
#define GEO_MID_ 130
#define FEAT_IN_ 2048

typedef unsigned short u16t;
typedef float f32x2 __attribute__((ext_vector_type(2)));

// ---- wave64 reductions in the VALU pipe (DPP), identity-preserving ----
#define DPP_STEP_MAX(ctrl) \
  t=(unsigned)__builtin_amdgcn_update_dpp((int)v,(int)v,(ctrl),0xf,0xf,false); \
  v=(t>v)?t:v;
#define DPP_STEP_MIN(ctrl) \
  t=(unsigned)__builtin_amdgcn_update_dpp((int)v,(int)v,(ctrl),0xf,0xf,false); \
  v=(t<v)?t:v;

__device__ __forceinline__ unsigned wave_max_u32(unsigned v){
  unsigned t;
  DPP_STEP_MAX(0x111) DPP_STEP_MAX(0x112) DPP_STEP_MAX(0x114) DPP_STEP_MAX(0x118)
  DPP_STEP_MAX(0x142) DPP_STEP_MAX(0x143)
  return (unsigned)__builtin_amdgcn_readlane((int)v,63);
}
__device__ __forceinline__ unsigned wave_min_u32(unsigned v){
  unsigned t;
  DPP_STEP_MIN(0x111) DPP_STEP_MIN(0x112) DPP_STEP_MIN(0x114) DPP_STEP_MIN(0x118)
  DPP_STEP_MIN(0x142) DPP_STEP_MIN(0x143)
  return (unsigned)__builtin_amdgcn_readlane((int)v,63);
}

// ---------------------------------------------------------------- FPS v4
// Proven 256-thr/4-wave structure + packed-f32x2 dist update. Every piece
// HW-verified: (1) packed formulation bit-identical to scalar _rn chain
// (r2 vs r4: identical outputs); (2) NO dynamic index into vector arrays
// (r7 scratch lesson) — owner coords come from an LDS xyz table (r6,
// correct) via a SPECULATIVE per-lane ds_read_b128 of the lane's own
// candidate, issued before the DPP chains (latency hidden; only the owner's
// value is used); (3) selection = proven always-2-phase DPP (r10 two-strike:
// no tree argmax, no ballot shortcut); (4) proven publish/merge: u64 key +
// float4 coords in parallel. Pair p = pts j=p (x-half, idx tid+256p) and
// j=p+8 (y-half, idx tid+256(p+8)): all x-half idx < y-half; strict > keeps
// smallest p per half; ywin strict -> tie prefers x-half == sequential scan.
__global__ __launch_bounds__(256) void fps_kernel(
    const float* __restrict__ xyz, float* __restrict__ outc)
{
  const int b = blockIdx.x, tid = threadIdx.x;
  const int wv = tid >> 6;
  const float* xb = xyz + (size_t)b * (N_*3);
  __shared__ __align__(16) float4 pl[N_];   // 64 KB staged xyz
  __shared__ unsigned long long kkey[2][4];
  __shared__ __align__(16) float4 kxyz[2][4];
  __shared__ float clist[M_][3];            // 12 KB

  for (int i=tid; i<N_; i+=256)
    pl[i] = make_float4(xb[i*3], xb[i*3+1], xb[i*3+2], 0.f);
  float lx=xb[0], ly=xb[1], lz=xb[2];
  if (tid==0){ clist[0][0]=lx; clist[0][1]=ly; clist[0][2]=lz; }
  __syncthreads();

  f32x2 PX[8], PY[8], PZ[8], DD[8];
#pragma unroll
  for (int p=0;p<8;p++){                    // static indices only
    float4 a = pl[tid + 256*p];             // j=p      (x-half)
    float4 c = pl[tid + 256*(p+8)];         // j=p+8    (y-half)
    PX[p] = (f32x2){a.x, c.x};
    PY[p] = (f32x2){a.y, c.y};
    PZ[p] = (f32x2){a.z, c.z};
    DD[p] = (f32x2){FLT_MAX, FLT_MAX};
  }

  for (int t=1;t<M_;t++){
    f32x2 lxv=(f32x2){lx,lx}, lyv=(f32x2){ly,ly}, lzv=(f32x2){lz,lz};
    f32x2 bd2=(f32x2){-FLT_MAX,-FLT_MAX};
    int bpx=0, bpy=0;
#pragma unroll
    for (int p=0;p<8;p++){                  // verbatim r2 packed body (proven bits)
      f32x2 dx=PX[p]-lxv, dy=PY[p]-lyv, dz=PZ[p]-lzv;
      f32x2 m1=dx*dx, m2=dy*dy, m3=dz*dz;
      f32x2 s=(m1+m2)+m3;                   // same op order as scalar _rn chain
      f32x2 nd=__builtin_elementwise_min(DD[p], s);
      DD[p]=nd;
      if (nd.x>bd2.x){ bd2.x=nd.x; bpx=p; } // strict > keeps smallest p
      if (nd.y>bd2.y){ bd2.y=nd.y; bpy=p; }
    }
    bool ywin = (bd2.y > bd2.x);            // tie -> x-half (smaller idx)
    float bd = ywin ? bd2.y : bd2.x;
    int   bi = tid + 256*(ywin ? bpy+8 : bpx);
    float4 myc = pl[bi];                    // speculative own-candidate read;
                                            // latency hides under DPP chains
    unsigned db=__float_as_uint(bd);        // bd>=0 => raw bits order-monotone
    unsigned smax=wave_max_u32(db);
    unsigned cand=(db==smax)?(unsigned)bi:0x7FFFFFFFu;
    unsigned sbi=wave_min_u32(cand);
    // owner lane (sbi&255 == tid) publishes key+coords (parallel merge inputs)
    if ((unsigned)tid==(sbi&255u)){
      kkey[t&1][wv]=((unsigned long long)smax<<32)|(unsigned)(0xFFFFFFFFu-sbi);
      kxyz[t&1][wv]=myc;
    }
    __syncthreads();
    // merge 4 wave candidates: higher dist wins, tie -> smaller index
    const unsigned long long* kp=kkey[t&1];
    const float4* cp=kxyz[t&1];
    unsigned long long k0=kp[0],k1=kp[1],k2=kp[2],k3=kp[3];
    float4 c0=cp[0],c1=cp[1],c2=cp[2],c3=cp[3];
    if (k1>k0){ k0=k1; c0=c1; }
    if (k3>k2){ k2=k3; c2=c3; }
    if (k2>k0){ k0=k2; c0=c2; }
    lx=c0.x; ly=c0.y; lz=c0.z;
    if (tid==0){ clist[t][0]=lx; clist[t][1]=ly; clist[t][2]=lz; }
  }
  __syncthreads();
  // bulk centroid write (one global pass, off the critical loop)
  for (int e=tid; e<M_; e+=256){
    size_t cb=((size_t)b*M_+(size_t)e)*3;
    outc[cb]=clist[e][0]; outc[cb+1]=clist[e][1]; outc[cb+2]=clist[e][2];
  }
}

// ---------------------------------------------------------------- KNN
// PROVEN wave-parallel-refill version (r11: pass, ~200us total gain).
__global__ __launch_bounds__(256) void knn_kernel(
    const float* __restrict__ xyz, const float* __restrict__ outc,
    u16t* __restrict__ gidx16)
{
  const int w = blockIdx.x*4 + (threadIdx.x>>6);
  const int lane = threadIdx.x & 63;
  const int b = w >> 10;
  const float* xb = xyz + (size_t)b*(N_*3);
  float cx=outc[(size_t)w*3], cy=outc[(size_t)w*3+1], cz=outc[(size_t)w*3+2];
  float c2=__fadd_rn(__fadd_rn(__fmul_rn(cx,cx),__fmul_rn(cy,cy)),__fmul_rn(cz,cz));

  float lv=FLT_MAX; int lj=0;
#pragma unroll
  for (int j=0;j<64;j++){
    int i = lane + 64*j;
    float xx=xb[i*3], xy=xb[i*3+1], xz=xb[i*3+2];
    float x2=__fadd_rn(__fadd_rn(__fmul_rn(xx,xx),__fmul_rn(xy,xy)),__fmul_rn(xz,xz));
    float dt=__fadd_rn(__fadd_rn(__fmul_rn(cx,xx),__fmul_rn(cy,xy)),__fmul_rn(cz,xz));
    float d=__fsub_rn(__fadd_rn(c2,x2),__fmul_rn(2.f,dt));
    if (d<lv){ lv=d; lj=j; }               // strict <: smallest j attaining min
  }
  unsigned long long cons = 0ull;          // my consumed slots
  const int wb = w*K_;
  for (int k=0;k<K_;k++){
    unsigned u=__float_as_uint(lv);
    u = (u&0x80000000u) ? ~u : (u|0x80000000u);   // order-preserving transform
    unsigned smin=wave_min_u32(u);
    unsigned cand=(u==smin)?(unsigned)(lane+64*lj):0xFFFFFFFFu;
    unsigned widx=wave_min_u32(cand);
    if (lane==0) gidx16[wb+k]=(u16t)widx;
    int owner=(int)(widx & 63u);
    int slot =(int)(widx >> 6);
    if (lane==owner) cons |= (1ull<<(unsigned)slot);
    if (k==K_-1) break;                    // nothing consumes the last refill
    // broadcast owner's consumed mask (owner is wave-uniform)
    unsigned clo=(unsigned)__builtin_amdgcn_readlane((int)(unsigned)cons, owner);
    unsigned chi=(unsigned)__builtin_amdgcn_readlane((int)(unsigned)(cons>>32), owner);
    unsigned long long ocons=((unsigned long long)chi<<32)|(unsigned long long)clo;
    // wave-parallel refill: lane s recomputes owner's slot s (bit-exact)
    int ip = owner + 64*lane;
    float xx=xb[ip*3], xy=xb[ip*3+1], xz=xb[ip*3+2];
    float x2=__fadd_rn(__fadd_rn(__fmul_rn(xx,xx),__fmul_rn(xy,xy)),__fmul_rn(xz,xz));
    float dt=__fadd_rn(__fadd_rn(__fmul_rn(cx,xx),__fmul_rn(cy,xy)),__fmul_rn(cz,xz));
    float d=__fsub_rn(__fadd_rn(c2,x2),__fmul_rn(2.f,dt));
    unsigned uj=__float_as_uint(d);
    uj=(uj&0x80000000u)?~uj:(uj|0x80000000u);
    if ((ocons>>(unsigned)lane)&1ull) uj=0xFFFFFFFFu;   // exclude consumed
    unsigned smin2=wave_min_u32(uj);
    unsigned cs=(uj==smin2)?(unsigned)lane:64u;
    unsigned sslot=wave_min_u32(cs);                    // smallest slot at min
    float dnew=__uint_as_float((unsigned)__builtin_amdgcn_readlane(__float_as_int(d),(int)sslot));
    if (lane==owner){ lv=dnew; lj=(int)sslot; }
  }
}

// ---------------------------------------------------------------- GEO fused (GEMM-style)
// (unchanged, proven)
__global__ __launch_bounds__(256) void geo_kernel(
    const float* __restrict__ xyz, const float* __restrict__ outc,
    const u16t* __restrict__ gidx16, const float* __restrict__ W1,
    const float* __restrict__ Wout, float* __restrict__ xout)
{
  __shared__ float smem[160*33 + 64*128 + 32];
  float (*Es)[33]  = (float(*)[33])smem;
  float (*Hs)[33]  = (float(*)[33])smem;
  float (*Ws)[128] = (float(*)[128])(smem + 160*33);
  float* ssv = smem + 160*33 + 64*128;

  const int t=threadIdx.x;
  const int g0=blockIdx.x*32;
  for (int p=t; p<1024; p+=256){
    int g=p>>5, kk=p&31;
    int gg=g0+g, b=gg>>10;
    int idx=gidx16[gg*K_+kk];
    const float* pt = xyz + ((size_t)b*N_+(size_t)idx)*3;
    const float* cc = outc + (size_t)gg*3;
    float dx=__fsub_rn(pt[0],cc[0]);
    float dy=__fsub_rn(pt[1],cc[1]);
    float dz=__fsub_rn(pt[2],cc[2]);
    float sq=__fadd_rn(__fadd_rn(__fmul_rn(dx,dx),__fmul_rn(dy,dy)),__fmul_rn(dz,dz));
    int r=5*kk;
    Es[r][g]=dx; Es[r+1][g]=dy; Es[r+2][g]=dz;
    Es[r+3][g]=-1.f; Es[r+4][g]=__fmul_rn(-0.5f,sq);
  }
  const int gsub=t>>4, hsub=t&15, h0=hsub*8;
  const int hw=t>>1;
  float acc[2][8];
#pragma unroll
  for (int a=0;a<2;a++)
#pragma unroll
    for (int j=0;j<8;j++) acc[a][j]=0.f;
  __syncthreads();

  for (int c=0;c<3;c++){
    int i0=c*64;
    if (c<2){
      int fw0=(t&1)*32;
      const float* wr = W1 + (size_t)hw*GEO_IN_ + i0 + fw0;
      float4 wv[8];
#pragma unroll
      for (int e=0;e<8;e++) wv[e]=((const float4*)wr)[e];
#pragma unroll
      for (int e=0;e<8;e++){
        Ws[fw0+4*e+0][hw]=wv[e].x;
        Ws[fw0+4*e+1][hw]=wv[e].y;
        Ws[fw0+4*e+2][hw]=wv[e].z;
        Ws[fw0+4*e+3][hw]=wv[e].w;
      }
    } else {
      int fw0=(t&1)*16;
      const float* wr = W1 + (size_t)hw*GEO_IN_ + 128 + fw0;
      float4 wv[4];
#pragma unroll
      for (int e=0;e<4;e++) wv[e]=((const float4*)wr)[e];
#pragma unroll
      for (int e=0;e<4;e++){
        Ws[fw0+4*e+0][hw]=wv[e].x;
        Ws[fw0+4*e+1][hw]=wv[e].y;
        Ws[fw0+4*e+2][hw]=wv[e].z;
        Ws[fw0+4*e+3][hw]=wv[e].w;
      }
    }
    __syncthreads();
    int len=(c==2)?32:64;
    for (int k2=0;k2<len;k2++){
      float x0=Es[i0+k2][2*gsub], x1=Es[i0+k2][2*gsub+1];
      const float* wp=&Ws[k2][h0];
      float4 wa=*(const float4*)wp;
      float4 wb=*(const float4*)(wp+4);
      acc[0][0]=__builtin_fmaf(x0,wa.x,acc[0][0]);
      acc[0][1]=__builtin_fmaf(x0,wa.y,acc[0][1]);
      acc[0][2]=__builtin_fmaf(x0,wa.z,acc[0][2]);
      acc[0][3]=__builtin_fmaf(x0,wa.w,acc[0][3]);
      acc[0][4]=__builtin_fmaf(x0,wb.x,acc[0][4]);
      acc[0][5]=__builtin_fmaf(x0,wb.y,acc[0][5]);
      acc[0][6]=__builtin_fmaf(x0,wb.z,acc[0][6]);
      acc[0][7]=__builtin_fmaf(x0,wb.w,acc[0][7]);
      acc[1][0]=__builtin_fmaf(x1,wa.x,acc[1][0]);
      acc[1][1]=__builtin_fmaf(x1,wa.y,acc[1][1]);
      acc[1][2]=__builtin_fmaf(x1,wa.z,acc[1][2]);
      acc[1][3]=__builtin_fmaf(x1,wa.w,acc[1][3]);
      acc[1][4]=__builtin_fmaf(x1,wb.x,acc[1][4]);
      acc[1][5]=__builtin_fmaf(x1,wb.y,acc[1][5]);
      acc[1][6]=__builtin_fmaf(x1,wb.z,acc[1][6]);
      acc[1][7]=__builtin_fmaf(x1,wb.w,acc[1][7]);
    }
    __syncthreads();
  }
#pragma unroll
  for (int a=0;a<2;a++)
#pragma unroll
    for (int j=0;j<8;j++)
      Hs[h0+j][2*gsub+a]=acc[a][j];
  __syncthreads();
  if (t<32){
    float ss=0.f;
    for (int h=0;h<H_;h++){ float v=Hs[h][t]; ss=__builtin_fmaf(v,v,ss); }
    ssv[t]=__fmul_rn(-0.5f,ss);
  }
#pragma unroll
  for (int a=0;a<2;a++)
#pragma unroll
    for (int j=0;j<8;j++) acc[a][j]=0.f;
  for (int c=0;c<2;c++){
    int i0=c*64;
    int fw0=(t&1)*32;
    const float* wr = Wout + (size_t)hw*GEO_MID_ + i0 + fw0;
    float2 wv2[16];
#pragma unroll
    for (int e=0;e<16;e++) wv2[e]=((const float2*)wr)[e];
    __syncthreads();
#pragma unroll
    for (int e=0;e<16;e++){
      Ws[fw0+2*e+0][hw]=wv2[e].x;
      Ws[fw0+2*e+1][hw]=wv2[e].y;
    }
    __syncthreads();
    for (int k2=0;k2<64;k2++){
      float x0=Hs[i0+k2][2*gsub], x1=Hs[i0+k2][2*gsub+1];
      const float* wp=&Ws[k2][h0];
      float4 wa=*(const float4*)wp;
      float4 wb=*(const float4*)(wp+4);
      acc[0][0]=__builtin_fmaf(x0,wa.x,acc[0][0]);
      acc[0][1]=__builtin_fmaf(x0,wa.y,acc[0][1]);
      acc[0][2]=__builtin_fmaf(x0,wa.z,acc[0][2]);
      acc[0][3]=__builtin_fmaf(x0,wa.w,acc[0][3]);
      acc[0][4]=__builtin_fmaf(x0,wb.x,acc[0][4]);
      acc[0][5]=__builtin_fmaf(x0,wb.y,acc[0][5]);
      acc[0][6]=__builtin_fmaf(x0,wb.z,acc[0][6]);
      acc[0][7]=__builtin_fmaf(x0,wb.w,acc[0][7]);
      acc[1][0]=__builtin_fmaf(x1,wa.x,acc[1][0]);
      acc[1][1]=__builtin_fmaf(x1,wa.y,acc[1][1]);
      acc[1][2]=__builtin_fmaf(x1,wa.z,acc[1][2]);
      acc[1][3]=__builtin_fmaf(x1,wa.w,acc[1][3]);
      acc[1][4]=__builtin_fmaf(x1,wb.x,acc[1][4]);
      acc[1][5]=__builtin_fmaf(x1,wb.y,acc[1][5]);
      acc[1][6]=__builtin_fmaf(x1,wb.z,acc[1][6]);
      acc[1][7]=__builtin_fmaf(x1,wb.w,acc[1][7]);
    }
  }
#pragma unroll
  for (int j=0;j<8;j++){
    int o=h0+j;
    float2 we=*(const float2*)(Wout + (size_t)o*GEO_MID_ + 128);
#pragma unroll
    for (int a=0;a<2;a++){
      float v=acc[a][j];
      v=__builtin_fmaf(-1.f, we.x, v);
      v=__builtin_fmaf(ssv[2*gsub+a], we.y, v);
      xout[(size_t)(g0+2*gsub+a)*256 + o]=v;
    }
  }
}

// ---------------------------------------------------------------- FEAT fused
// (unchanged, proven)
__global__ __launch_bounds__(256) void feat_kernel(
    const float* __restrict__ feats, const u16t* __restrict__ gidx16,
    const float* __restrict__ W1, const float* __restrict__ b1,
    const float* __restrict__ Wout, const float* __restrict__ bout,
    float* __restrict__ xout)
{
  __shared__ float smem[12800];                      // 51.2 KB
  float (*Xs)[68]  = (float(*)[68])smem;             // [64][68]
  float (*Ws)[128] = (float(*)[128])(smem + 64*68);  // [64][128]
  float (*Hs)[68]  = (float(*)[68])smem;             // [128][68] alias (post K-loop)
  float (*WoS)[128]= (float(*)[128])(smem + 128*68); // [32][128]
  const int t=threadIdx.x;
  const int g0=blockIdx.x*64;
  const int gsub=t>>4;
  const int h0=(t&15)*8;
  const int glx=t>>2, fq=(t&3)*16;
  const int hw=t>>1, fw0=(t&1)*32;
  const int fw1=(t&1)*16;
  const int gld=g0+glx, bld=gld>>10;
  float acc[4][8];
#pragma unroll
  for (int a=0;a<4;a++)
#pragma unroll
    for (int j=0;j<8;j++) acc[a][j]=0.f;

  for (int kk=0;kk<K_;kk++){
    int nidx=gidx16[gld*K_+kk];
    const float* fr=feats + ((size_t)bld*N_+(size_t)nidx)*FEAT_ + fq;
    float4 p[4];
#pragma unroll
    for (int e=0;e<4;e++) p[e]=((const float4*)fr)[e];
    const float* wr=W1 + (size_t)hw*FEAT_IN_ + kk*64 + fw0;
    float4 wv[8];
#pragma unroll
    for (int e=0;e<8;e++) wv[e]=((const float4*)wr)[e];
#pragma unroll
    for (int e=0;e<4;e++){
      Xs[fq+4*e+0][glx]=p[e].x;
      Xs[fq+4*e+1][glx]=p[e].y;
      Xs[fq+4*e+2][glx]=p[e].z;
      Xs[fq+4*e+3][glx]=p[e].w;
    }
#pragma unroll
    for (int e=0;e<8;e++){
      Ws[fw0+4*e+0][hw]=wv[e].x;
      Ws[fw0+4*e+1][hw]=wv[e].y;
      Ws[fw0+4*e+2][hw]=wv[e].z;
      Ws[fw0+4*e+3][hw]=wv[e].w;
    }
    __syncthreads();
#pragma unroll 4
    for (int k2=0;k2<64;k2++){
      float4 xv=*(const float4*)&Xs[k2][4*gsub];
      const float* wp=&Ws[k2][h0];
      float4 wa=*(const float4*)wp;
      float4 wb=*(const float4*)(wp+4);
      float xr[4]={xv.x,xv.y,xv.z,xv.w};
      float wf[8]={wa.x,wa.y,wa.z,wa.w,wb.x,wb.y,wb.z,wb.w};
#pragma unroll
      for (int a=0;a<4;a++)
#pragma unroll
        for (int j=0;j<8;j++)
          acc[a][j]=__builtin_fmaf(xr[a],wf[j],acc[a][j]);
    }
    __syncthreads();
  }
#pragma unroll
  for (int j=0;j<8;j++){
    float bv=b1[h0+j];
#pragma unroll
    for (int a=0;a<4;a++)
      Hs[h0+j][4*gsub+a]=fmaxf(__fadd_rn(acc[a][j],bv),0.f);
  }
  float ac2[4][8];
#pragma unroll
  for (int a=0;a<4;a++)
#pragma unroll
    for (int j=0;j<8;j++) ac2[a][j]=0.f;
  for (int c=0;c<4;c++){
    const float* wr2=Wout + (size_t)hw*H_ + c*32 + fw1;
    float4 w2[4];
#pragma unroll
    for (int e=0;e<4;e++) w2[e]=((const float4*)wr2)[e];
    __syncthreads();
#pragma unroll
    for (int e=0;e<4;e++){
      WoS[fw1+4*e+0][hw]=w2[e].x;
      WoS[fw1+4*e+1][hw]=w2[e].y;
      WoS[fw1+4*e+2][hw]=w2[e].z;
      WoS[fw1+4*e+3][hw]=w2[e].w;
    }
    __syncthreads();
#pragma unroll 4
    for (int k2=0;k2<32;k2++){
      float4 xv=*(const float4*)&Hs[c*32+k2][4*gsub];
      const float* wp=&WoS[k2][h0];
      float4 wa=*(const float4*)wp;
      float4 wb=*(const float4*)(wp+4);
      float xr[4]={xv.x,xv.y,xv.z,xv.w};
      float wf[8]={wa.x,wa.y,wa.z,wa.w,wb.x,wb.y,wb.z,wb.w};
#pragma unroll
      for (int a=0;a<4;a++)
#pragma unroll
        for (int j=0;j<8;j++)
          ac2[a][j]=__builtin_fmaf(xr[a],wf[j],ac2[a][j]);
    }
  }
#pragma unroll
  for (int j=0;j<8;j++){
    float bv=bout[h0+j];
#pragma unroll
    for (int a=0;a<4;a++)
      xout[(size_t)(g0+4*gsub+a)*256+128+h0+j]=__fadd_rn(ac2[a][j],bv);
  }
}

// ----------------------------------------------------------------
extern "C" void kernel_launch(void* const* d_in, const int* in_sizes, int n_in,
                              void* d_out, int out_size, void* d_ws, size_t ws_size,
                              hipStream_t stream) {
  const float* xyz  =(const float*)d_in[0];
  const float* feats=(const float*)d_in[1];
  const float* gW1  =(const float*)d_in[2];
  const float* gWout=(const float*)d_in[3];
  const float* fW1  =(const float*)d_in[4];
  const float* fb1  =(const float*)d_in[5];
  const float* fWout=(const float*)d_in[6];
  const float* fbout=(const float*)d_in[7];
  float* out=(float*)d_out;

  u16t* gidx16=(u16t*)d_ws;          // 1 MB
  float* xout = out + (size_t)B_*M_*3;

  fps_kernel <<<dim3(B_),          dim3(256), 0, stream>>>(xyz, out);
  knn_kernel <<<dim3((B_*M_)/4),   dim3(256), 0, stream>>>(xyz, out, gidx16);
  geo_kernel <<<dim3((B_*M_)/32),  dim3(256), 0, stream>>>(xyz, out, gidx16, gW1, gWout, xout);
  feat_kernel<<<dim3((B_*M_)/64),  dim3(256), 0, stream>>>(feats, gidx16, fW1, fb1, fWout, fbout, xout);
}